// Round 8
// baseline (398.003 us; speedup 1.0000x reference)
//
#include <hip/hip_runtime.h>
#include <hip/hip_cooperative_groups.h>

namespace cg = cooperative_groups;

typedef unsigned short u16;
typedef unsigned int u32;

#define D_MODEL 1024
#define N_HEADS 16
#define D_HEAD 64
#define WIN 256
#define SEQ 2048
#define BATCH 2
#define NROWS (BATCH*SEQ)          // 4096 token rows

typedef short frag_ab __attribute__((ext_vector_type(8)));   // 8 bf16 (4 VGPRs)
typedef float frag_cd __attribute__((ext_vector_type(4)));   // 4 fp32 (16x16 C/D)
typedef float f32x16 __attribute__((ext_vector_type(16)));   // 32x32 C/D
typedef u16 u16x8 __attribute__((ext_vector_type(8)));

__device__ __forceinline__ u16 f2bf(float f) {
    union { float f; u32 u; } x; x.f = f;
    u32 r = x.u + 0x7fffu + ((x.u >> 16) & 1u);   // RNE
    return (u16)(r >> 16);
}

__device__ __forceinline__ void load_lds16(const void* g, void* l) {
    __builtin_amdgcn_global_load_lds(
        (const __attribute__((address_space(1))) void*)g,
        (__attribute__((address_space(3))) void*)l, 16, 0, 0);
}

// ---------------- shared-memory union for all phases (34,816 B -> 4 blocks/CU) ----------------
union Smem {
    float tile[32][33];                                            //  4,224 B (prep transpose)
    struct { u16 As[128 * 64]; u16 Bs[128 * 64]; } g;              // 32,768 B (gemm staging)
    u16 cs[128 * 136];                                             // 34,816 B (gemm bf16 epilogue)
    struct { u16 Ks[2][64 * 64]; u16 Vt[64 * 72]; u16 ps[4][16 * 72]; } a;  // 34,816 B (attn)
};

// ---------------- prep: transpose-cast tile ----------------
__device__ __forceinline__ void transpose_tile(const float* __restrict__ W, u16* __restrict__ WT,
                                               int K, int N, int n0, int k0,
                                               int scale_rows, float scale, float (*tile)[33]) {
    int x = threadIdx.x & 31, y = threadIdx.x >> 5;   // 32 x 8
#pragma unroll
    for (int r = 0; r < 4; r++)
        tile[y + 8 * r][x] = W[(size_t)(k0 + y + 8 * r) * N + n0 + x];
    __syncthreads();
#pragma unroll
    for (int r = 0; r < 4; r++) {
        int nrow = n0 + y + 8 * r;
        float v = tile[x][y + 8 * r];
        if (nrow < scale_rows) v *= scale;
        WT[(size_t)nrow * K + k0 + x] = f2bf(v);
    }
}

__device__ __forceinline__ void prep_unit(u32 u, const float* __restrict__ x,
                                          const float* __restrict__ W_qkv,
                                          const float* __restrict__ W_out,
                                          u16* __restrict__ xb, u16* __restrict__ wqkvT,
                                          u16* __restrict__ woutT, float qscale, Smem& sm) {
    if (u < 4096) {                       // cast x: 1 float4/thread
        int idx = u * 256 + threadIdx.x;
        float4 v = ((const float4*)x)[idx];
        ushort4 o;
        o.x = f2bf(v.x); o.y = f2bf(v.y); o.z = f2bf(v.z); o.w = f2bf(v.w);
        ((ushort4*)xb)[idx] = o;
    } else if (u < 7168) {                // W_qkv [1024,3072] -> [3072,1024], q rows scaled
        int t = u - 4096;
        transpose_tile(W_qkv, wqkvT, D_MODEL, 3 * D_MODEL, (t % 96) * 32, (t / 96) * 32,
                       D_MODEL, qscale, sm.tile);
    } else {                              // W_out [1024,1024] -> [1024,1024]
        int t = u - 7168;
        transpose_tile(W_out, woutT, D_MODEL, D_MODEL, (t & 31) * 32, (t >> 5) * 32,
                       0, 1.0f, sm.tile);
    }
}

// ---------------- gemm tile: C[BMx128] = A[BM,K] * BT[128,K]^T, BK=64, 32x32x16 ----------------
// Staging: global_load_lds w/ XOR-chunk swizzle on the fetch side. Frag maps verified
// m74/m101: A/B lane m=lane&31, k=(lane>>5)*8+j; C/D col=lane&31, row=(reg&3)+8*(reg>>2)+4*(lane>>5).
template <bool BF16_OUT, int BM>
__device__ __forceinline__ void gemm_tile(const u16* __restrict__ A, const u16* __restrict__ BT,
                                          void* __restrict__ C, int N, int K,
                                          int m0, int n0, Smem& sm) {
    constexpr int MT = BM / 64;
    const int tid = threadIdx.x;
    const int wave = tid >> 6, lane = tid & 63;
    const int wm = (wave >> 1) * (BM / 2), wn = (wave & 1) * 64;
    const int l32 = lane & 31, kh = lane >> 5;

    f32x16 acc[MT][2] = {};

    const int r0 = tid >> 3;                   // 0..31
    const int w  = (tid & 7) ^ (r0 & 7);       // swizzled source chunk
    const u16* aP = A  + (size_t)(m0 + r0) * K + w * 8;
    const u16* bP = BT + (size_t)(n0 + r0) * K + w * 8;

    for (int k0 = 0; k0 < K; k0 += 64) {
        __syncthreads();                       // also guards smem vs previous phase/tile
#pragma unroll
        for (int u = 0; u < BM / 32; u++)
            load_lds16(aP + (size_t)(32 * u) * K + k0, &sm.g.As[(tid + 256 * u) * 8]);
#pragma unroll
        for (int u = 0; u < 4; u++)
            load_lds16(bP + (size_t)(32 * u) * K + k0, &sm.g.Bs[(tid + 256 * u) * 8]);
        __syncthreads();

#pragma unroll
        for (int kk = 0; kk < 4; kk++) {
            const int csel = ((kk * 2 + kh) ^ (l32 & 7)) * 8;
            frag_ab af[MT], bf[2];
#pragma unroll
            for (int t = 0; t < MT; t++)
                af[t] = *(const frag_ab*)&sm.g.As[(wm + t * 32 + l32) * 64 + csel];
#pragma unroll
            for (int t = 0; t < 2; t++)
                bf[t] = *(const frag_ab*)&sm.g.Bs[(wn + t * 32 + l32) * 64 + csel];
#pragma unroll
            for (int mt = 0; mt < MT; mt++)
#pragma unroll
                for (int nt = 0; nt < 2; nt++)
                    acc[mt][nt] = __builtin_amdgcn_mfma_f32_32x32x16_bf16(af[mt], bf[nt], acc[mt][nt], 0, 0, 0);
        }
    }

    if constexpr (BF16_OUT) {
        __syncthreads();
#pragma unroll
        for (int mt = 0; mt < MT; mt++)
#pragma unroll
            for (int nt = 0; nt < 2; nt++) {
                int col = wn + nt * 32 + l32;
#pragma unroll
                for (int reg = 0; reg < 16; reg++) {
                    int row = wm + mt * 32 + (reg & 3) + 8 * (reg >> 2) + 4 * kh;
                    sm.cs[row * 136 + col] = f2bf(acc[mt][nt][reg]);
                }
            }
        __syncthreads();
        const int cc = tid & 15, rb = tid >> 4;
#pragma unroll
        for (int i = 0; i < BM / 16; i++) {
            int row = rb + 16 * i;
            u16x8 vv = *(const u16x8*)&sm.cs[row * 136 + cc * 8];
            *(u16x8*)((u16*)C + (size_t)(m0 + row) * N + n0 + cc * 8) = vv;
        }
    } else {
#pragma unroll
        for (int mt = 0; mt < MT; mt++)
#pragma unroll
            for (int nt = 0; nt < 2; nt++) {
                int col = n0 + wn + nt * 32 + l32;
#pragma unroll
                for (int reg = 0; reg < 16; reg++) {
                    int row = m0 + wm + mt * 32 + (reg & 3) + 8 * (reg >> 2) + 4 * kh;
                    ((float*)C)[(size_t)row * N + col] = acc[mt][nt][reg];
                }
            }
    }
}

// ---------------- attn tile: 64 q-rows of one (b,h); K-dbuf pipelined (round-5 proven) ----------
__device__ __forceinline__ void attn_tile(u32 tile_id, const u16* __restrict__ qkv,
                                          u16* __restrict__ out, Smem& sm) {
    const int tid = threadIdx.x;
    const int wave = tid >> 6, lane = tid & 63;
    const int quad = lane >> 4, c16 = lane & 15;

    const int qc = tile_id & 31;
    const int h  = (tile_id >> 5) & 15;
    const int b  = tile_id >> 9;
    const int q0 = qc * 64;
    const int qw0 = q0 + wave * 16;

    frag_ab qf[2];
    {
        const u16* qrow = qkv + (size_t)(b * SEQ + qw0 + c16) * 3072 + h * 64;
        qf[0] = *(const frag_ab*)(qrow + quad * 8);
        qf[1] = *(const frag_ab*)(qrow + 32 + quad * 8);
    }

    float m_r[4], l_r[4];
    frag_cd acc[4] = {};

    const int ntiles = qc < 4 ? qc + 1 : 5;

    const int krow = wave * 16 + (lane >> 3);
    const int kchunk = (lane & 7) ^ (lane >> 3);
    const int vj2 = (tid & 31) * 2, vd8 = tid >> 5;

    const u16* kbase = qkv + (size_t)(b * SEQ + krow) * 3072 + 1024 + h * 64 + kchunk * 8;
    const u16* vbase = qkv + (size_t)(b * SEQ + vj2) * 3072 + 2048 + h * 64 + vd8 * 8;

    u16x8 va, vb;
    {
        const u16* g = kbase + (size_t)q0 * 3072;
        load_lds16(g,            &sm.a.Ks[0][krow * 64 + (lane & 7) * 8]);
        load_lds16(g + 8 * 3072, &sm.a.Ks[0][(krow + 8) * 64 + (lane & 7) * 8]);
        const u16* gv = vbase + (size_t)q0 * 3072;
        va = *(const u16x8*)gv;
        vb = *(const u16x8*)(gv + 3072);
#pragma unroll
        for (int dd = 0; dd < 8; dd++)
            *(u32*)&sm.a.Vt[(vd8 * 8 + dd) * 72 + vj2] = (u32)va[dd] | ((u32)vb[dd] << 16);
    }

    for (int t = 0; t < ntiles; t++) {
        const int cur = t & 1, nxt = cur ^ 1;
        const int j0 = q0 - 64 * t;
        __syncthreads();                 // Ks[cur] + Vt staged & visible
        const bool pre = (t + 1 < ntiles);
        if (pre) {                       // prefetch t+1: K -> LDS[nxt] (async), V -> regs
            const u16* g = kbase + (size_t)(j0 - 64) * 3072;
            load_lds16(g,            &sm.a.Ks[nxt][krow * 64 + (lane & 7) * 8]);
            load_lds16(g + 8 * 3072, &sm.a.Ks[nxt][(krow + 8) * 64 + (lane & 7) * 8]);
            const u16* gv = vbase + (size_t)(j0 - 64) * 3072;
            va = *(const u16x8*)gv;
            vb = *(const u16x8*)(gv + 3072);
        }

        frag_cd s[4] = {};
#pragma unroll
        for (int kb = 0; kb < 4; kb++) {
            frag_ab kf0 = *(const frag_ab*)&sm.a.Ks[cur][(kb * 16 + c16) * 64 + ((quad    ) ^ (c16 & 7)) * 8];
            frag_ab kf1 = *(const frag_ab*)&sm.a.Ks[cur][(kb * 16 + c16) * 64 + ((4 + quad) ^ (c16 & 7)) * 8];
            s[kb] = __builtin_amdgcn_mfma_f32_16x16x32_bf16(qf[0], kf0, s[kb], 0, 0, 0);
            s[kb] = __builtin_amdgcn_mfma_f32_16x16x32_bf16(qf[1], kf1, s[kb], 0, 0, 0);
        }

        if (t == 0) {
#pragma unroll
            for (int reg = 0; reg < 4; reg++) {
                const int i = qw0 + quad * 4 + reg;
#pragma unroll
                for (int kb = 0; kb < 4; kb++)
                    if (q0 + kb * 16 + c16 > i) s[kb][reg] = -1e30f;
            }
        } else if (t == 4) {
#pragma unroll
            for (int reg = 0; reg < 4; reg++) {
                const int i = qw0 + quad * 4 + reg;
#pragma unroll
                for (int kb = 0; kb < 4; kb++)
                    if (j0 + kb * 16 + c16 + WIN <= i) s[kb][reg] = -1e30f;
            }
        }

        float mt_[4];
#pragma unroll
        for (int reg = 0; reg < 4; reg++)
            mt_[reg] = fmaxf(fmaxf(s[0][reg], s[1][reg]), fmaxf(s[2][reg], s[3][reg]));
#pragma unroll
        for (int off = 1; off < 16; off <<= 1)
#pragma unroll
            for (int reg = 0; reg < 4; reg++) mt_[reg] = fmaxf(mt_[reg], __shfl_xor(mt_[reg], off));

        float alpha[4];
        if (t == 0) {
#pragma unroll
            for (int reg = 0; reg < 4; reg++) m_r[reg] = mt_[reg];
        } else {
#pragma unroll
            for (int reg = 0; reg < 4; reg++) {
                float mn = fmaxf(m_r[reg], mt_[reg]);
                alpha[reg] = __builtin_amdgcn_exp2f(m_r[reg] - mn);
                m_r[reg] = mn;
            }
        }

        float rs[4] = {0.f, 0.f, 0.f, 0.f};
#pragma unroll
        for (int kb = 0; kb < 4; kb++)
#pragma unroll
            for (int reg = 0; reg < 4; reg++) {
                float p = __builtin_amdgcn_exp2f(s[kb][reg] - m_r[reg]);
                union { float f; u32 u; } pu; pu.f = p;
                sm.a.ps[wave][(quad * 4 + reg) * 72 + kb * 16 + c16] = (u16)(pu.u >> 16);  // RTZ
                rs[reg] += p;
            }
#pragma unroll
        for (int off = 1; off < 16; off <<= 1)
#pragma unroll
            for (int reg = 0; reg < 4; reg++) rs[reg] += __shfl_xor(rs[reg], off);

        if (t == 0) {
#pragma unroll
            for (int reg = 0; reg < 4; reg++) l_r[reg] = rs[reg];
        } else {
#pragma unroll
            for (int reg = 0; reg < 4; reg++) l_r[reg] = l_r[reg] * alpha[reg] + rs[reg];
#pragma unroll
            for (int dblk = 0; dblk < 4; dblk++)
#pragma unroll
                for (int reg = 0; reg < 4; reg++) acc[dblk][reg] *= alpha[reg];
        }

#pragma unroll
        for (int js = 0; js < 2; js++) {
            frag_ab pf = *(const frag_ab*)&sm.a.ps[wave][c16 * 72 + js * 32 + quad * 8];
#pragma unroll
            for (int dblk = 0; dblk < 4; dblk++) {
                frag_ab vf = *(const frag_ab*)&sm.a.Vt[(dblk * 16 + c16) * 72 + js * 32 + quad * 8];
                acc[dblk] = __builtin_amdgcn_mfma_f32_16x16x32_bf16(pf, vf, acc[dblk], 0, 0, 0);
            }
        }

        if (pre) {
            __syncthreads();             // all waves done with PV(t) -> Vt overwrite safe
#pragma unroll
            for (int dd = 0; dd < 8; dd++)
                *(u32*)&sm.a.Vt[(vd8 * 8 + dd) * 72 + vj2] = (u32)va[dd] | ((u32)vb[dd] << 16);
        }
    }

    float inv[4];
#pragma unroll
    for (int reg = 0; reg < 4; reg++) inv[reg] = 1.f / l_r[reg];
#pragma unroll
    for (int dblk = 0; dblk < 4; dblk++)
#pragma unroll
        for (int reg = 0; reg < 4; reg++)
            out[(size_t)(b * SEQ + qw0 + quad * 4 + reg) * 1024 + h * 64 + dblk * 16 + c16] =
                f2bf(acc[dblk][reg] * inv[reg]);
}

// ---------------- the fused cooperative pipeline ----------------
// P0 prep -> sync -> P1 gemm1 (768 tiles) -> sync -> P2 attn (1024 tiles) -> sync -> P3 gemm2 (512)
__global__ __launch_bounds__(256, 4) void mega_kernel(
    const float* __restrict__ x, const float* __restrict__ W_qkv, const float* __restrict__ W_out,
    u16* __restrict__ xb, u16* __restrict__ wqkvT, u16* __restrict__ woutT,
    u16* __restrict__ qkvb, u16* __restrict__ attnb, float* __restrict__ out, float qscale) {
    __shared__ Smem sm;
    cg::grid_group grid = cg::this_grid();

    for (u32 u = blockIdx.x; u < 8192; u += gridDim.x) {
        prep_unit(u, x, W_qkv, W_out, xb, wqkvT, woutT, qscale, sm);
        __syncthreads();                  // sm.tile reuse across grid-stride iterations
    }
    grid.sync();
    // gemm1: qkv = xb @ wqkvT^T, 32 m-blocks x 24 n-blocks (m fastest -> consecutive share B)
    for (u32 t = blockIdx.x; t < 768; t += gridDim.x)
        gemm_tile<true, 128>(xb, wqkvT, qkvb, 3 * D_MODEL, D_MODEL,
                             (int)(t & 31) * 128, (int)(t >> 5) * 128, sm);
    grid.sync();
    for (u32 t = blockIdx.x; t < 1024; t += gridDim.x) {
        __syncthreads();                  // guard Ks/Vt prologue vs previous tile's PV reads
        attn_tile(t, qkvb, attnb, sm);
    }
    grid.sync();
    // gemm2: out = attnb @ woutT^T, 64 m-blocks x 8 n-blocks (m fastest)
    for (u32 t = blockIdx.x; t < 512; t += gridDim.x)
        gemm_tile<false, 64>(attnb, woutT, out, D_MODEL, D_MODEL,
                             (int)(t & 63) * 64, (int)(t >> 6) * 128, sm);
}

extern "C" void kernel_launch(void* const* d_in, const int* in_sizes, int n_in,
                              void* d_out, int out_size, void* d_ws, size_t ws_size,
                              hipStream_t stream) {
    const float* x     = (const float*)d_in[0];   // [2,2048,1024]
    const float* W_qkv = (const float*)d_in[1];   // [1024,3072]
    const float* W_out = (const float*)d_in[2];   // [1024,1024]
    float* out = (float*)d_out;                   // [2,2048,1024]

    char* ws = (char*)d_ws;
    u16* xb    = (u16*)(ws);                       //  8 MB : x bf16 [4096,1024]
    u16* wqkvT = (u16*)(ws + 8388608);             //  6 MB : W_qkv^T bf16 [3072,1024] (q rows pre-scaled)
    u16* woutT = (u16*)(ws + 14680064);            //  2 MB : W_out^T bf16 [1024,1024]
    u16* qkvb  = (u16*)(ws + 16777216);            // 24 MB : qkv bf16 [4096,3072]
    u16* attnb = (u16*)(ws + 41943040);            //  8 MB : attn out bf16 [4096,1024]

    float qscale = 0.125f * 1.4426950408889634f;   // 1/sqrt(64) * log2(e)

    // grid = co-resident capacity (grid-stride phases are correct for any grid size)
    int occ = 0;
    hipOccupancyMaxActiveBlocksPerMultiprocessor(&occ, mega_kernel, 256, 0);
    if (occ < 1) occ = 1;
    int nblk = occ * 256;                          // 256 CUs on MI355X
    if (nblk > 1024) nblk = 1024;                  // no phase has more than 1024 tiles

    void* args[] = { (void*)&x, (void*)&W_qkv, (void*)&W_out, (void*)&xb, (void*)&wqkvT,
                     (void*)&woutT, (void*)&qkvb, (void*)&attnb, (void*)&out, (void*)&qscale };
    hipLaunchCooperativeKernel(mega_kernel, dim3(nblk), dim3(256), args, 0, stream);
}

// Round 9
// 151.620 us; speedup vs baseline: 2.6250x; 2.6250x over previous
//
#include <hip/hip_runtime.h>

typedef unsigned short u16;
typedef unsigned int u32;

#define D_MODEL 1024
#define N_HEADS 16
#define D_HEAD 64
#define WIN 256
#define SEQ 2048
#define BATCH 2
#define NROWS (BATCH*SEQ)          // 4096 token rows

typedef short frag_ab __attribute__((ext_vector_type(8)));   // 8 bf16 (4 VGPRs)
typedef float frag_cd __attribute__((ext_vector_type(4)));   // 4 fp32 (16x16 C/D)
typedef float f32x16 __attribute__((ext_vector_type(16)));   // 32x32 C/D
typedef u16 u16x8 __attribute__((ext_vector_type(8)));

__device__ __forceinline__ u16 f2bf(float f) {
    union { float f; u32 u; } x; x.f = f;
    u32 r = x.u + 0x7fffu + ((x.u >> 16) & 1u);   // RNE
    return (u16)(r >> 16);
}

__device__ __forceinline__ void load_lds16(const void* g, void* l) {
    __builtin_amdgcn_global_load_lds(
        (const __attribute__((address_space(1))) void*)g,
        (__attribute__((address_space(3))) void*)l, 16, 0, 0);
}

// ---------------- transpose-cast tile helper (caller supplies LDS) ----------------
__device__ __forceinline__ void transpose_tile(const float* __restrict__ W, u16* __restrict__ WT,
                                               int K, int N, int n0, int k0,
                                               int scale_rows, float scale, float (*tile)[33]) {
    int x = threadIdx.x & 31, y = threadIdx.x >> 5;   // 32 x 8
#pragma unroll
    for (int r = 0; r < 4; r++)
        tile[y + 8 * r][x] = W[(size_t)(k0 + y + 8 * r) * N + n0 + x];
    __syncthreads();
#pragma unroll
    for (int r = 0; r < 4; r++) {
        int nrow = n0 + y + 8 * r;
        float v = tile[x][y + 8 * r];
        if (nrow < scale_rows) v *= scale;
        WT[(size_t)nrow * K + k0 + x] = f2bf(v);
    }
}

// ---------------- prep: cast x + transpose-cast W_qkv ----------------
__global__ __launch_bounds__(256) void prep_kernel(const float* __restrict__ x,
                                                   const float* __restrict__ W_qkv,
                                                   u16* __restrict__ xb,
                                                   u16* __restrict__ wqkvT,
                                                   float qscale) {
    __shared__ float tile[32][33];
    const int bid = blockIdx.x;
    if (bid < 4096) {
        int idx = bid * 256 + threadIdx.x;
        float4 v = ((const float4*)x)[idx];
        ushort4 o;
        o.x = f2bf(v.x); o.y = f2bf(v.y); o.z = f2bf(v.z); o.w = f2bf(v.w);
        ((ushort4*)xb)[idx] = o;
    } else {
        int t = bid - 4096;                       // N=3072: 96 x 32 tiles
        transpose_tile(W_qkv, wqkvT, D_MODEL, 3 * D_MODEL, (t % 96) * 32, (t / 96) * 32,
                       D_MODEL, qscale, tile);
    }
}

// ---------------- bf16 GEMM: C[BM x 128] = A[M,K] * BT[N,K]^T, BK=64, 32x32x16 ----------------
// 1D grid, XCD-aware decode (block%8 = XCD [m09]): xcd = B&7, s = B>>3,
// n_blk = xcd*NPER + s/MB, m_blk = s%MB  -> each XCD owns NPER n-blocks, its
// B-slice stays resident in that XCD's 4 MB L2 while it streams A tiles.
// Staging: global_load_lds w/ XOR-chunk swizzle on the fetch side. Frag maps
// verified m74/m101: A/B lane m=lane&31, k=(lane>>5)*8+j;
// C/D col=lane&31, row=(reg&3)+8*(reg>>2)+4*(lane>>5).
template <bool BF16_OUT, int BM, int MB, int NPER>
__global__ __launch_bounds__(256, 4) void gemm_bk64(const u16* __restrict__ A,
                                                    const u16* __restrict__ BT,
                                                    void* __restrict__ C,
                                                    int M, int N, int K) {
    constexpr int MT = BM / 64;
    __shared__ union SMem {
        struct { u16 As[BM * 64]; u16 Bs[128 * 64]; } s;
        u16 cs[BF16_OUT ? BM * 136 : 1];          // epilogue transpose tile (bf16 path)
    } sm;
    const int tid = threadIdx.x;
    const int xcd = blockIdx.x & 7, sblk = blockIdx.x >> 3;
    const int m0 = (sblk % MB) * BM;
    const int n0 = (xcd * NPER + sblk / MB) * 128;
    const int wave = tid >> 6, lane = tid & 63;
    const int wm = (wave >> 1) * (BM / 2), wn = (wave & 1) * 64;
    const int l32 = lane & 31, kh = lane >> 5;

    f32x16 acc[MT][2] = {};

    const int r0 = tid >> 3;                   // 0..31
    const int w  = (tid & 7) ^ (r0 & 7);       // swizzled source chunk
    const u16* aP = A  + (size_t)(m0 + r0) * K + w * 8;
    const u16* bP = BT + (size_t)(n0 + r0) * K + w * 8;

    for (int k0 = 0; k0 < K; k0 += 64) {
        __syncthreads();
#pragma unroll
        for (int u = 0; u < BM / 32; u++)
            load_lds16(aP + (size_t)(32 * u) * K + k0, &sm.s.As[(tid + 256 * u) * 8]);
#pragma unroll
        for (int u = 0; u < 4; u++)
            load_lds16(bP + (size_t)(32 * u) * K + k0, &sm.s.Bs[(tid + 256 * u) * 8]);
        __syncthreads();

#pragma unroll
        for (int kk = 0; kk < 4; kk++) {
            const int csel = ((kk * 2 + kh) ^ (l32 & 7)) * 8;
            frag_ab af[MT], bf[2];
#pragma unroll
            for (int t = 0; t < MT; t++)
                af[t] = *(const frag_ab*)&sm.s.As[(wm + t * 32 + l32) * 64 + csel];
#pragma unroll
            for (int t = 0; t < 2; t++)
                bf[t] = *(const frag_ab*)&sm.s.Bs[(wn + t * 32 + l32) * 64 + csel];
#pragma unroll
            for (int mt = 0; mt < MT; mt++)
#pragma unroll
                for (int nt = 0; nt < 2; nt++)
                    acc[mt][nt] = __builtin_amdgcn_mfma_f32_32x32x16_bf16(af[mt], bf[nt], acc[mt][nt], 0, 0, 0);
        }
    }

    if constexpr (BF16_OUT) {
        __syncthreads();
#pragma unroll
        for (int mt = 0; mt < MT; mt++)
#pragma unroll
            for (int nt = 0; nt < 2; nt++) {
                int col = wn + nt * 32 + l32;
#pragma unroll
                for (int reg = 0; reg < 16; reg++) {
                    int row = wm + mt * 32 + (reg & 3) + 8 * (reg >> 2) + 4 * kh;
                    sm.cs[row * 136 + col] = f2bf(acc[mt][nt][reg]);
                }
            }
        __syncthreads();
        const int cc = tid & 15, rb = tid >> 4;
#pragma unroll
        for (int i = 0; i < BM / 16; i++) {
            int row = rb + 16 * i;
            u16x8 vv = *(const u16x8*)&sm.cs[row * 136 + cc * 8];
            *(u16x8*)((u16*)C + (size_t)(m0 + row) * N + n0 + cc * 8) = vv;
        }
    } else {
#pragma unroll
        for (int mt = 0; mt < MT; mt++)
#pragma unroll
            for (int nt = 0; nt < 2; nt++) {
                int col = n0 + wn + nt * 32 + l32;
#pragma unroll
                for (int reg = 0; reg < 16; reg++) {
                    int row = m0 + wm + mt * 32 + (reg & 3) + 8 * (reg >> 2) + 4 * kh;
                    ((float*)C)[(size_t)row * N + col] = acc[mt][nt][reg];
                }
            }
    }
}

// ---------------- MFMA flash attention (sliding window), pipelined ----------------
// Blocks [0,1024): attention, decode head=B&31, qc=B>>5 -> all 32 q-tiles of a
// head land on XCD head%8; per-XCD KV working set = 4 heads x 512 KB = 2 MB,
// L2-resident across the ~5x KV re-read.
// Blocks [1024,2048): W_out transpose-cast (reuses Ks LDS; woutT consumed by gemm2).
__global__ __launch_bounds__(256) void attn_kernel(const u16* __restrict__ qkv, u16* __restrict__ out,
                                                   const float* __restrict__ W_out,
                                                   u16* __restrict__ woutT) {
    __shared__ u16 Ks[2][64 * 64];       // XOR-chunk-swizzled: chunk c of row r at c^(r&7)
    __shared__ u16 Vt[64 * 72];          // Vt[d][j], row pad +8 (single buffer)
    __shared__ u16 ps[4][16 * 72];       // per-wave P tile, row pad +8

    if (blockIdx.x >= 1024) {            // W_out transpose blocks
        int t = blockIdx.x - 1024;       // 1024 tiles of 32x32
        transpose_tile(W_out, woutT, D_MODEL, D_MODEL, (t & 31) * 32, (t >> 5) * 32,
                       0, 1.0f, (float(*)[33])&Ks[0][0]);
        return;
    }

    const int tid = threadIdx.x;
    const int wave = tid >> 6, lane = tid & 63;
    const int quad = lane >> 4, c16 = lane & 15;

    const int bh = blockIdx.x & 31;      // b*16+h  -> XCD = bh%8
    const int qc = blockIdx.x >> 5;      // 0..31
    const int h  = bh & 15;
    const int b  = bh >> 4;
    const int q0 = qc * 64;
    const int qw0 = q0 + wave * 16;

    frag_ab qf[2];
    {
        const u16* qrow = qkv + (size_t)(b * SEQ + qw0 + c16) * 3072 + h * 64;
        qf[0] = *(const frag_ab*)(qrow + quad * 8);
        qf[1] = *(const frag_ab*)(qrow + 32 + quad * 8);
    }

    float m_r[4], l_r[4];
    frag_cd acc[4] = {};

    const int ntiles = qc < 4 ? qc + 1 : 5;

    const int krow = wave * 16 + (lane >> 3);
    const int kchunk = (lane & 7) ^ (lane >> 3);
    const int vj2 = (tid & 31) * 2, vd8 = tid >> 5;

    const u16* kbase = qkv + (size_t)(b * SEQ + krow) * 3072 + 1024 + h * 64 + kchunk * 8;
    const u16* vbase = qkv + (size_t)(b * SEQ + vj2) * 3072 + 2048 + h * 64 + vd8 * 8;

    u16x8 va, vb;
    {
        const u16* g = kbase + (size_t)q0 * 3072;
        load_lds16(g,            &Ks[0][krow * 64 + (lane & 7) * 8]);
        load_lds16(g + 8 * 3072, &Ks[0][(krow + 8) * 64 + (lane & 7) * 8]);
        const u16* gv = vbase + (size_t)q0 * 3072;
        va = *(const u16x8*)gv;
        vb = *(const u16x8*)(gv + 3072);
#pragma unroll
        for (int dd = 0; dd < 8; dd++)
            *(u32*)&Vt[(vd8 * 8 + dd) * 72 + vj2] = (u32)va[dd] | ((u32)vb[dd] << 16);
    }

    for (int t = 0; t < ntiles; t++) {
        const int cur = t & 1, nxt = cur ^ 1;
        const int j0 = q0 - 64 * t;
        __syncthreads();                 // Ks[cur] + Vt staged & visible
        const bool pre = (t + 1 < ntiles);
        if (pre) {                       // prefetch t+1: K -> LDS[nxt] (async), V -> regs
            const u16* g = kbase + (size_t)(j0 - 64) * 3072;
            load_lds16(g,            &Ks[nxt][krow * 64 + (lane & 7) * 8]);
            load_lds16(g + 8 * 3072, &Ks[nxt][(krow + 8) * 64 + (lane & 7) * 8]);
            const u16* gv = vbase + (size_t)(j0 - 64) * 3072;
            va = *(const u16x8*)gv;
            vb = *(const u16x8*)(gv + 3072);
        }

        frag_cd s[4] = {};
#pragma unroll
        for (int kb = 0; kb < 4; kb++) {
            frag_ab kf0 = *(const frag_ab*)&Ks[cur][(kb * 16 + c16) * 64 + ((quad    ) ^ (c16 & 7)) * 8];
            frag_ab kf1 = *(const frag_ab*)&Ks[cur][(kb * 16 + c16) * 64 + ((4 + quad) ^ (c16 & 7)) * 8];
            s[kb] = __builtin_amdgcn_mfma_f32_16x16x32_bf16(qf[0], kf0, s[kb], 0, 0, 0);
            s[kb] = __builtin_amdgcn_mfma_f32_16x16x32_bf16(qf[1], kf1, s[kb], 0, 0, 0);
        }

        if (t == 0) {
#pragma unroll
            for (int reg = 0; reg < 4; reg++) {
                const int i = qw0 + quad * 4 + reg;
#pragma unroll
                for (int kb = 0; kb < 4; kb++)
                    if (q0 + kb * 16 + c16 > i) s[kb][reg] = -1e30f;
            }
        } else if (t == 4) {
#pragma unroll
            for (int reg = 0; reg < 4; reg++) {
                const int i = qw0 + quad * 4 + reg;
#pragma unroll
                for (int kb = 0; kb < 4; kb++)
                    if (j0 + kb * 16 + c16 + WIN <= i) s[kb][reg] = -1e30f;
            }
        }

        float mt_[4];
#pragma unroll
        for (int reg = 0; reg < 4; reg++)
            mt_[reg] = fmaxf(fmaxf(s[0][reg], s[1][reg]), fmaxf(s[2][reg], s[3][reg]));
#pragma unroll
        for (int off = 1; off < 16; off <<= 1)
#pragma unroll
            for (int reg = 0; reg < 4; reg++) mt_[reg] = fmaxf(mt_[reg], __shfl_xor(mt_[reg], off));

        float alpha[4];
        if (t == 0) {
#pragma unroll
            for (int reg = 0; reg < 4; reg++) m_r[reg] = mt_[reg];
        } else {
#pragma unroll
            for (int reg = 0; reg < 4; reg++) {
                float mn = fmaxf(m_r[reg], mt_[reg]);
                alpha[reg] = __builtin_amdgcn_exp2f(m_r[reg] - mn);
                m_r[reg] = mn;
            }
        }

        float rs[4] = {0.f, 0.f, 0.f, 0.f};
#pragma unroll
        for (int kb = 0; kb < 4; kb++)
#pragma unroll
            for (int reg = 0; reg < 4; reg++) {
                float p = __builtin_amdgcn_exp2f(s[kb][reg] - m_r[reg]);
                union { float f; u32 u; } pu; pu.f = p;
                ps[wave][(quad * 4 + reg) * 72 + kb * 16 + c16] = (u16)(pu.u >> 16);  // RTZ
                rs[reg] += p;
            }
#pragma unroll
        for (int off = 1; off < 16; off <<= 1)
#pragma unroll
            for (int reg = 0; reg < 4; reg++) rs[reg] += __shfl_xor(rs[reg], off);

        if (t == 0) {
#pragma unroll
            for (int reg = 0; reg < 4; reg++) l_r[reg] = rs[reg];
        } else {
#pragma unroll
            for (int reg = 0; reg < 4; reg++) l_r[reg] = l_r[reg] * alpha[reg] + rs[reg];
#pragma unroll
            for (int dblk = 0; dblk < 4; dblk++)
#pragma unroll
                for (int reg = 0; reg < 4; reg++) acc[dblk][reg] *= alpha[reg];
        }

#pragma unroll
        for (int js = 0; js < 2; js++) {
            frag_ab pf = *(const frag_ab*)&ps[wave][c16 * 72 + js * 32 + quad * 8];
#pragma unroll
            for (int dblk = 0; dblk < 4; dblk++) {
                frag_ab vf = *(const frag_ab*)&Vt[(dblk * 16 + c16) * 72 + js * 32 + quad * 8];
                acc[dblk] = __builtin_amdgcn_mfma_f32_16x16x32_bf16(pf, vf, acc[dblk], 0, 0, 0);
            }
        }

        if (pre) {
            __syncthreads();             // all waves done with PV(t) -> Vt overwrite safe
#pragma unroll
            for (int dd = 0; dd < 8; dd++)
                *(u32*)&Vt[(vd8 * 8 + dd) * 72 + vj2] = (u32)va[dd] | ((u32)vb[dd] << 16);
        }
    }

    float inv[4];
#pragma unroll
    for (int reg = 0; reg < 4; reg++) inv[reg] = 1.f / l_r[reg];
#pragma unroll
    for (int dblk = 0; dblk < 4; dblk++)
#pragma unroll
        for (int reg = 0; reg < 4; reg++)
            out[(size_t)(b * SEQ + qw0 + quad * 4 + reg) * 1024 + h * 64 + dblk * 16 + c16] =
                f2bf(acc[dblk][reg] * inv[reg]);
}

extern "C" void kernel_launch(void* const* d_in, const int* in_sizes, int n_in,
                              void* d_out, int out_size, void* d_ws, size_t ws_size,
                              hipStream_t stream) {
    const float* x     = (const float*)d_in[0];   // [2,2048,1024]
    const float* W_qkv = (const float*)d_in[1];   // [1024,3072]
    const float* W_out = (const float*)d_in[2];   // [1024,1024]
    float* out = (float*)d_out;                   // [2,2048,1024]

    char* ws = (char*)d_ws;
    u16* xb    = (u16*)(ws);                       //  8 MB : x bf16 [4096,1024]
    u16* wqkvT = (u16*)(ws + 8388608);             //  6 MB : W_qkv^T bf16 [3072,1024] (q rows pre-scaled)
    u16* woutT = (u16*)(ws + 14680064);            //  2 MB : W_out^T bf16 [1024,1024]
    u16* qkvb  = (u16*)(ws + 16777216);            // 24 MB : qkv bf16 [4096,3072]
    u16* attnb = (u16*)(ws + 41943040);            //  8 MB : attn out bf16 [4096,1024]

    const float QSCALE = 0.125f * 1.4426950408889634f;  // 1/sqrt(64) * log2(e)

    prep_kernel<<<7168, 256, 0, stream>>>(x, W_qkv, xb, wqkvT, QSCALE);
    // gemm1: qkv = xb @ wqkvT^T. 768 blocks, XCD-swizzled (3 n-blocks per XCD).
    gemm_bk64<true, 128, 32, 3><<<768, 256, 0, stream>>>(
        xb, wqkvT, qkvb, NROWS, 3 * D_MODEL, D_MODEL);
    // attn (1024 blocks, head-per-XCD swizzle) + W_out transpose (1024 blocks)
    attn_kernel<<<2048, 256, 0, stream>>>(qkvb, attnb, W_out, woutT);
    // gemm2: out = attnb @ woutT^T. 512 blocks, XCD-swizzled (1 n-block per XCD).
    gemm_bk64<false, 64, 64, 1><<<512, 256, 0, stream>>>(
        attnb, woutT, out, NROWS, D_MODEL, D_MODEL);
}